// Round 5
// baseline (441.769 us; speedup 1.0000x reference)
//
#include <hip/hip_runtime.h>

#define TWO_PI_F 6.283185307179586f

__device__ __forceinline__ float clamp02pi(float x) {
    return fminf(fmaxf(x, 0.0f), TWO_PI_F);
}

// Clements mesh forward, N=512. Block b owns columns (2b, 2b+1).
// State in LDS: P[c][p] = {re(row 2p), im(row 2p), re(row 2p+1), im(row 2p+1)}
// for column 2b+c. 256 scan steps of [2 even layers | barrier | 2 odd layers |
// barrier]. Even layer pair p = rows (2p,2p+1) = P[c][p] (thread p local).
// Odd layer pair p = rows (2p+1,2p+2) = P[c][p].zw + P[c][p+1].xy, touched by
// thread p ONLY -> byte-disjoint, race-free with barriers only at the
// even<->odd ownership transitions. (Mesh identical to R4 — ran clean; only
// the output epilogue changed this round.)
__global__ __launch_bounds__(256) void mesh_kernel(
    const float* __restrict__ pe,   // [512][256] pc_even_phases
    const float* __restrict__ po,   // [512][255] pc_odd_phases
    const float* __restrict__ pout, // [512]      pc_out_phases
    const float* __restrict__ le,   // [512][256] mmi_loss_even
    const float* __restrict__ ie,   // [512][256] mmi_imb_even
    const float* __restrict__ lo,   // [512][255] mmi_loss_odd
    const float* __restrict__ io,   // [512][255] mmi_imb_odd
    float* __restrict__ out,
    const int out_size)             // 262144 -> real plane; 524288 -> planar re||im
{
    const int p = threadIdx.x;   // pair index 0..255
    const int b = blockIdx.x;    // column-pair index 0..255

    __shared__ float4 P[2][256];

    P[0][p] = (p == b) ? make_float4(1.0f, 0.0f, 0.0f, 0.0f)
                       : make_float4(0.0f, 0.0f, 0.0f, 0.0f);
    P[1][p] = (p == b) ? make_float4(0.0f, 0.0f, 1.0f, 0.0f)
                       : make_float4(0.0f, 0.0f, 0.0f, 0.0f);
    // First even phase reads only P[*][p] (own entry) — no barrier needed.

#pragma unroll 1
    for (int i = 0; i < 256; ++i) {
        // ---- batch-load all coefficients for this step ----
        const int e0 = (2 * i) * 256 + p, e1 = e0 + 256;
        const float pe0 = pe[e0], le0 = le[e0], ie0 = ie[e0];
        const float pe1 = pe[e1], le1 = le[e1], ie1 = ie[e1];
        float po0 = 0.0f, lo0 = 0.0f, io0 = 0.0f;
        float po1 = 0.0f, lo1 = 0.0f, io1 = 0.0f;
        if (p < 255) {
            const int o0 = (2 * i) * 255 + p, o1 = o0 + 255;
            po0 = po[o0]; lo0 = lo[o0]; io0 = io[o0];
            po1 = po[o1]; lo1 = lo[o1]; io1 = io[o1];
        }

        // ---- two even layers (thread-local on P[c][p]) ----
        float4 v0 = P[0][p];
        float4 v1 = P[1][p];
#pragma unroll
        for (int j = 0; j < 2; ++j) {
            float s, c;
            __sincosf(clamp02pi(j ? pe1 : pe0), &s, &c);
            const float a  = sqrtf(1.0f - (j ? le1 : le0));
            const float tt = a * sqrtf(0.5f + (j ? ie1 : ie0));
            const float rr = a * sqrtf(0.5f - (j ? ie1 : ie0));
            {   // top = .xy (row 2p, phased), bot = .zw (row 2p+1)
                const float ptr_ = c * v0.x - s * v0.y;
                const float pti_ = c * v0.y + s * v0.x;
                v0 = make_float4(tt * ptr_ - rr * v0.w, tt * pti_ + rr * v0.z,
                                 tt * v0.z - rr * pti_, tt * v0.w + rr * ptr_);
            }
            {
                const float ptr_ = c * v1.x - s * v1.y;
                const float pti_ = c * v1.y + s * v1.x;
                v1 = make_float4(tt * ptr_ - rr * v1.w, tt * pti_ + rr * v1.z,
                                 tt * v1.z - rr * pti_, tt * v1.w + rr * ptr_);
            }
        }
        P[0][p] = v0;
        P[1][p] = v1;
        __syncthreads();

        // ---- two odd layers (thread p owns rows 2p+1 = [p].zw, 2p+2 = [p+1].xy) ----
        if (p < 255) {
            float2 top0 = make_float2(P[0][p].z, P[0][p].w);
            float2 bot0 = make_float2(P[0][p + 1].x, P[0][p + 1].y);
            float2 top1 = make_float2(P[1][p].z, P[1][p].w);
            float2 bot1 = make_float2(P[1][p + 1].x, P[1][p + 1].y);
#pragma unroll
            for (int j = 0; j < 2; ++j) {
                float s, c;
                __sincosf(clamp02pi(j ? po1 : po0), &s, &c);
                const float a  = sqrtf(1.0f - (j ? lo1 : lo0));
                const float tt = a * sqrtf(0.5f + (j ? io1 : io0));
                const float rr = a * sqrtf(0.5f - (j ? io1 : io0));
                {
                    const float ptr_ = c * top0.x - s * top0.y;
                    const float pti_ = c * top0.y + s * top0.x;
                    const float nbx = tt * bot0.x - rr * pti_;
                    const float nby = tt * bot0.y + rr * ptr_;
                    top0 = make_float2(tt * ptr_ - rr * bot0.y, tt * pti_ + rr * bot0.x);
                    bot0 = make_float2(nbx, nby);
                }
                {
                    const float ptr_ = c * top1.x - s * top1.y;
                    const float pti_ = c * top1.y + s * top1.x;
                    const float nbx = tt * bot1.x - rr * pti_;
                    const float nby = tt * bot1.y + rr * ptr_;
                    top1 = make_float2(tt * ptr_ - rr * bot1.y, tt * pti_ + rr * bot1.x);
                    bot1 = make_float2(nbx, nby);
                }
            }
            P[0][p].z = top0.x; P[0][p].w = top0.y;
            P[0][p + 1].x = bot0.x; P[0][p + 1].y = bot0.y;
            P[1][p].z = top1.x; P[1][p].w = top1.y;
            P[1][p + 1].x = bot1.x; P[1][p + 1].y = bot1.y;
        }
        __syncthreads();
    }

    // ---- output phases (per row) ----
    const float4 v0 = P[0][p];   // rows 2p, 2p+1 of column 2b
    const float4 v1 = P[1][p];   // rows 2p, 2p+1 of column 2b+1
    float s0, c0, s1, c1;
    __sincosf(clamp02pi(pout[2 * p]),     &s0, &c0);
    __sincosf(clamp02pi(pout[2 * p + 1]), &s1, &c1);

    // w0 = row 2p  (cols 2b, 2b+1): {re0, im0, re1, im1}
    // w1 = row 2p+1(cols 2b, 2b+1)
    float4 w0, w1;
    w0.x = c0 * v0.x - s0 * v0.y;  w0.y = c0 * v0.y + s0 * v0.x;
    w0.z = c0 * v1.x - s0 * v1.y;  w0.w = c0 * v1.y + s0 * v1.x;
    w1.x = c1 * v0.z - s1 * v0.w;  w1.y = c1 * v0.w + s1 * v0.z;
    w1.z = c1 * v1.z - s1 * v1.w;  w1.w = c1 * v1.w + s1 * v1.z;

    const int i0 = (2 * p) * 512 + 2 * b;       // row 2p,   col 2b (element index)
    const int i1 = (2 * p + 1) * 512 + 2 * b;   // row 2p+1, col 2b

    if (out_size == 524288) {
        // Hypothesis B: planar float32 — re plane [0,262144) then im plane.
        *(float2*)(out + i0) = make_float2(w0.x, w0.z);
        *(float2*)(out + i1) = make_float2(w1.x, w1.z);
        *(float2*)(out + 262144 + i0) = make_float2(w0.y, w0.w);
        *(float2*)(out + 262144 + i1) = make_float2(w1.y, w1.w);
    } else {
        // Hypothesis A (primary): out_size == 262144, expected = Re(M),
        // row-major. Guarded — cannot fault regardless of true buffer size.
        if (i0 + 1 < out_size) *(float2*)(out + i0) = make_float2(w0.x, w0.z);
        if (i1 + 1 < out_size) *(float2*)(out + i1) = make_float2(w1.x, w1.z);
    }
}

extern "C" void kernel_launch(void* const* d_in, const int* in_sizes, int n_in,
                              void* d_out, int out_size, void* d_ws, size_t ws_size,
                              hipStream_t stream)
{
    const float* pe   = (const float*)d_in[0];  // pc_even_phases  [512][256]
    const float* po   = (const float*)d_in[1];  // pc_odd_phases   [512][255]
    const float* pout = (const float*)d_in[2];  // pc_out_phases   [512]
    const float* le   = (const float*)d_in[3];  // mmi_loss_even   [512][256]
    const float* ie   = (const float*)d_in[4];  // mmi_imb_even    [512][256]
    const float* lo   = (const float*)d_in[5];  // mmi_loss_odd    [512][255]
    const float* io   = (const float*)d_in[6];  // mmi_imb_odd     [512][255]

    mesh_kernel<<<256, 256, 0, stream>>>(pe, po, pout, le, ie, lo, io,
                                         (float*)d_out, out_size);
}

// Round 6
// 388.489 us; speedup vs baseline: 1.1371x; 1.1371x over previous
//
#include <hip/hip_runtime.h>

#define TWO_PI_F 6.283185307179586f

__device__ __forceinline__ float clamp02pi(float x) {
    return fminf(fmaxf(x, 0.0f), TWO_PI_F);
}

// ---------------------------------------------------------------------------
// Kernel 1: coefficient precompute. Layer k in [0,512), pair p in [0,256).
// coefE[k*256+p] = (cos, sin, t, r) for even layer k, pair (2p, 2p+1).
// coefO[k*256+p] = same for odd layer k, pair (2p+1, 2p+2); p=255 -> identity.
// Fully parallel (131072 threads), removes ALL trig/sqrt from the scan loop.
// ---------------------------------------------------------------------------
__global__ __launch_bounds__(256) void coef_kernel(
    const float* __restrict__ pe, const float* __restrict__ po,
    const float* __restrict__ le, const float* __restrict__ ie,
    const float* __restrict__ lo, const float* __restrict__ io,
    float4* __restrict__ coefE, float4* __restrict__ coefO)
{
    const int k = blockIdx.x;    // layer 0..511
    const int p = threadIdx.x;   // pair  0..255
    {
        const int idx = k * 256 + p;
        float s, c;
        sincosf(clamp02pi(pe[idx]), &s, &c);
        const float a = sqrtf(1.0f - le[idx]);
        coefE[k * 256 + p] = make_float4(c, s, a * sqrtf(0.5f + ie[idx]),
                                               a * sqrtf(0.5f - ie[idx]));
    }
    float4 q = make_float4(1.0f, 0.0f, 1.0f, 0.0f);
    if (p < 255) {
        const int idx = k * 255 + p;
        float s, c;
        sincosf(clamp02pi(po[idx]), &s, &c);
        const float a = sqrtf(1.0f - lo[idx]);
        q = make_float4(c, s, a * sqrtf(0.5f + io[idx]), a * sqrtf(0.5f - io[idx]));
    }
    coefO[k * 256 + p] = q;
}

// Couple (top, bot) with q = (c, s, t, r): top gets phase e^{i th}, then
//   top' = t*pt + i*r*bot ; bot' = i*r*pt + t*bot.
__device__ __forceinline__ void couple(const float4 q, float2& top, float2& bot)
{
    const float pr = q.x * top.x - q.y * top.y;
    const float pi = q.x * top.y + q.y * top.x;
    const float ntx = q.z * pr - q.w * bot.y;
    const float nty = q.z * pi + q.w * bot.x;
    const float nbx = q.z * bot.x - q.w * pi;
    const float nby = q.z * bot.y + q.w * pr;
    top = make_float2(ntx, nty);
    bot = make_float2(nbx, nby);
}

// ---------------------------------------------------------------------------
// Kernel 2: mesh scan, one column per block (512 blocks -> 2 blocks/CU for
// cross-block latency hiding at barriers). State in LDS as split float2
// arrays (8 B stride = 2-way bank aliasing = free):
//   T[p] = row 2p, B[p] = row 2p+1.
// Even layer pair p: (T[p], B[p])   — thread p only.
// Odd  layer pair p: (B[p], T[p+1]) — thread p only (byte-disjoint).
// Barriers only at the even<->odd ownership transitions (2 per step).
// ---------------------------------------------------------------------------
__global__ __launch_bounds__(256) void mesh_ws_kernel(
    const float4* __restrict__ coefE,
    const float4* __restrict__ coefO,
    const float* __restrict__ pout,
    float* __restrict__ out, const int out_size)
{
    const int p   = threadIdx.x;   // pair index 0..255
    const int col = blockIdx.x;    // column 0..511

    __shared__ float2 T[256];
    __shared__ float2 B[256];

    T[p] = make_float2((2 * p     == col) ? 1.0f : 0.0f, 0.0f);
    B[p] = make_float2((2 * p + 1 == col) ? 1.0f : 0.0f, 0.0f);
    // First even phase reads only this thread's own entries — no barrier.

#pragma unroll 1
    for (int i = 0; i < 256; ++i) {
        const int base = (2 * i) * 256 + p;
        const float4 e0 = coefE[base];
        const float4 e1 = coefE[base + 256];
        const float4 o0 = coefO[base];
        const float4 o1 = coefO[base + 256];

        // ---- two even layers: pair (2p, 2p+1) ----
        float2 top = T[p], bot = B[p];
        couple(e0, top, bot);
        couple(e1, top, bot);
        T[p] = top;
        B[p] = bot;
        __syncthreads();

        // ---- two odd layers: pair (2p+1, 2p+2) ----
        if (p < 255) {
            float2 t2 = B[p];       // row 2p+1
            float2 b2 = T[p + 1];   // row 2p+2
            couple(o0, t2, b2);
            couple(o1, t2, b2);
            B[p]     = t2;
            T[p + 1] = b2;
        }
        __syncthreads();
    }

    // ---- output phases (per row); expected output = Re(M), row-major ----
    const float2 top = T[p], bot = B[p];
    float s0, c0, s1, c1;
    __sincosf(clamp02pi(pout[2 * p]),     &s0, &c0);
    __sincosf(clamp02pi(pout[2 * p + 1]), &s1, &c1);
    const int i0 = (2 * p) * 512 + col;
    const int i1 = i0 + 512;
    if (i0 < out_size) out[i0] = c0 * top.x - s0 * top.y;
    if (i1 < out_size) out[i1] = c1 * bot.x - s1 * bot.y;
}

// ---------------------------------------------------------------------------
// Fallback (verbatim R5 kernel, known-passing) — used only if ws too small.
// ---------------------------------------------------------------------------
__global__ __launch_bounds__(256) void mesh_kernel(
    const float* __restrict__ pe, const float* __restrict__ po,
    const float* __restrict__ pout,
    const float* __restrict__ le, const float* __restrict__ ie,
    const float* __restrict__ lo, const float* __restrict__ io,
    float* __restrict__ out, const int out_size)
{
    const int p = threadIdx.x;
    const int b = blockIdx.x;

    __shared__ float4 P[2][256];

    P[0][p] = (p == b) ? make_float4(1.0f, 0.0f, 0.0f, 0.0f)
                       : make_float4(0.0f, 0.0f, 0.0f, 0.0f);
    P[1][p] = (p == b) ? make_float4(0.0f, 0.0f, 1.0f, 0.0f)
                       : make_float4(0.0f, 0.0f, 0.0f, 0.0f);

#pragma unroll 1
    for (int i = 0; i < 256; ++i) {
        const int e0 = (2 * i) * 256 + p, e1 = e0 + 256;
        const float pe0 = pe[e0], le0 = le[e0], ie0 = ie[e0];
        const float pe1 = pe[e1], le1 = le[e1], ie1 = ie[e1];
        float po0 = 0.0f, lo0 = 0.0f, io0 = 0.0f;
        float po1 = 0.0f, lo1 = 0.0f, io1 = 0.0f;
        if (p < 255) {
            const int o0 = (2 * i) * 255 + p, o1 = o0 + 255;
            po0 = po[o0]; lo0 = lo[o0]; io0 = io[o0];
            po1 = po[o1]; lo1 = lo[o1]; io1 = io[o1];
        }

        float4 v0 = P[0][p];
        float4 v1 = P[1][p];
#pragma unroll
        for (int j = 0; j < 2; ++j) {
            float s, c;
            __sincosf(clamp02pi(j ? pe1 : pe0), &s, &c);
            const float a  = sqrtf(1.0f - (j ? le1 : le0));
            const float tt = a * sqrtf(0.5f + (j ? ie1 : ie0));
            const float rr = a * sqrtf(0.5f - (j ? ie1 : ie0));
            {
                const float ptr_ = c * v0.x - s * v0.y;
                const float pti_ = c * v0.y + s * v0.x;
                v0 = make_float4(tt * ptr_ - rr * v0.w, tt * pti_ + rr * v0.z,
                                 tt * v0.z - rr * pti_, tt * v0.w + rr * ptr_);
            }
            {
                const float ptr_ = c * v1.x - s * v1.y;
                const float pti_ = c * v1.y + s * v1.x;
                v1 = make_float4(tt * ptr_ - rr * v1.w, tt * pti_ + rr * v1.z,
                                 tt * v1.z - rr * pti_, tt * v1.w + rr * ptr_);
            }
        }
        P[0][p] = v0;
        P[1][p] = v1;
        __syncthreads();

        if (p < 255) {
            float2 top0 = make_float2(P[0][p].z, P[0][p].w);
            float2 bot0 = make_float2(P[0][p + 1].x, P[0][p + 1].y);
            float2 top1 = make_float2(P[1][p].z, P[1][p].w);
            float2 bot1 = make_float2(P[1][p + 1].x, P[1][p + 1].y);
#pragma unroll
            for (int j = 0; j < 2; ++j) {
                float s, c;
                __sincosf(clamp02pi(j ? po1 : po0), &s, &c);
                const float a  = sqrtf(1.0f - (j ? lo1 : lo0));
                const float tt = a * sqrtf(0.5f + (j ? io1 : io0));
                const float rr = a * sqrtf(0.5f - (j ? io1 : io0));
                {
                    const float ptr_ = c * top0.x - s * top0.y;
                    const float pti_ = c * top0.y + s * top0.x;
                    const float nbx = tt * bot0.x - rr * pti_;
                    const float nby = tt * bot0.y + rr * ptr_;
                    top0 = make_float2(tt * ptr_ - rr * bot0.y, tt * pti_ + rr * bot0.x);
                    bot0 = make_float2(nbx, nby);
                }
                {
                    const float ptr_ = c * top1.x - s * top1.y;
                    const float pti_ = c * top1.y + s * top1.x;
                    const float nbx = tt * bot1.x - rr * pti_;
                    const float nby = tt * bot1.y + rr * ptr_;
                    top1 = make_float2(tt * ptr_ - rr * bot1.y, tt * pti_ + rr * bot1.x);
                    bot1 = make_float2(nbx, nby);
                }
            }
            P[0][p].z = top0.x; P[0][p].w = top0.y;
            P[0][p + 1].x = bot0.x; P[0][p + 1].y = bot0.y;
            P[1][p].z = top1.x; P[1][p].w = top1.y;
            P[1][p + 1].x = bot1.x; P[1][p + 1].y = bot1.y;
        }
        __syncthreads();
    }

    const float4 v0 = P[0][p];
    const float4 v1 = P[1][p];
    float s0, c0, s1, c1;
    __sincosf(clamp02pi(pout[2 * p]),     &s0, &c0);
    __sincosf(clamp02pi(pout[2 * p + 1]), &s1, &c1);

    float4 w0, w1;
    w0.x = c0 * v0.x - s0 * v0.y;  w0.y = c0 * v0.y + s0 * v0.x;
    w0.z = c0 * v1.x - s0 * v1.y;  w0.w = c0 * v1.y + s0 * v1.x;
    w1.x = c1 * v0.z - s1 * v0.w;  w1.y = c1 * v0.w + s1 * v0.z;
    w1.z = c1 * v1.z - s1 * v1.w;  w1.w = c1 * v1.w + s1 * v1.z;

    const int i0 = (2 * p) * 512 + 2 * b;
    const int i1 = (2 * p + 1) * 512 + 2 * b;
    if (i0 + 1 < out_size) *(float2*)(out + i0) = make_float2(w0.x, w0.z);
    if (i1 + 1 < out_size) *(float2*)(out + i1) = make_float2(w1.x, w1.z);
}

extern "C" void kernel_launch(void* const* d_in, const int* in_sizes, int n_in,
                              void* d_out, int out_size, void* d_ws, size_t ws_size,
                              hipStream_t stream)
{
    const float* pe   = (const float*)d_in[0];  // pc_even_phases  [512][256]
    const float* po   = (const float*)d_in[1];  // pc_odd_phases   [512][255]
    const float* pout = (const float*)d_in[2];  // pc_out_phases   [512]
    const float* le   = (const float*)d_in[3];  // mmi_loss_even   [512][256]
    const float* ie   = (const float*)d_in[4];  // mmi_imb_even    [512][256]
    const float* lo   = (const float*)d_in[5];  // mmi_loss_odd    [512][255]
    const float* io   = (const float*)d_in[6];  // mmi_imb_odd     [512][255]

    const size_t need = (size_t)2 * 512 * 256 * sizeof(float4);  // 4 MB
    if (ws_size >= need) {
        float4* coefE = (float4*)d_ws;
        float4* coefO = coefE + 512 * 256;
        coef_kernel<<<512, 256, 0, stream>>>(pe, po, le, ie, lo, io, coefE, coefO);
        mesh_ws_kernel<<<512, 256, 0, stream>>>(coefE, coefO, pout,
                                                (float*)d_out, out_size);
    } else {
        mesh_kernel<<<256, 256, 0, stream>>>(pe, po, pout, le, ie, lo, io,
                                             (float*)d_out, out_size);
    }
}

// Round 7
// 273.198 us; speedup vs baseline: 1.6170x; 1.4220x over previous
//
#include <hip/hip_runtime.h>

#define TWO_PI_F 6.283185307179586f

__device__ __forceinline__ float clamp02pi(float x) {
    return fminf(fmaxf(x, 0.0f), TWO_PI_F);
}

// ---------------------------------------------------------------------------
// Kernel 1: coefficient precompute (unchanged from R6 — verified).
// coefE[k*256+p] = (cos, sin, t, r) for even layer k, pair (2p, 2p+1).
// coefO[k*256+p] = same for odd layer k, pair (2p+1, 2p+2); p=255 = identity.
// ---------------------------------------------------------------------------
__global__ __launch_bounds__(256) void coef_kernel(
    const float* __restrict__ pe, const float* __restrict__ po,
    const float* __restrict__ le, const float* __restrict__ ie,
    const float* __restrict__ lo, const float* __restrict__ io,
    float4* __restrict__ coefE, float4* __restrict__ coefO)
{
    const int k = blockIdx.x;    // layer 0..511
    const int p = threadIdx.x;   // pair  0..255
    {
        const int idx = k * 256 + p;
        float s, c;
        sincosf(clamp02pi(pe[idx]), &s, &c);
        const float a = sqrtf(1.0f - le[idx]);
        coefE[k * 256 + p] = make_float4(c, s, a * sqrtf(0.5f + ie[idx]),
                                               a * sqrtf(0.5f - ie[idx]));
    }
    float4 q = make_float4(1.0f, 0.0f, 1.0f, 0.0f);
    if (p < 255) {
        const int idx = k * 255 + p;
        float s, c;
        sincosf(clamp02pi(po[idx]), &s, &c);
        const float a = sqrtf(1.0f - lo[idx]);
        q = make_float4(c, s, a * sqrtf(0.5f + io[idx]), a * sqrtf(0.5f - io[idx]));
    }
    coefO[k * 256 + p] = q;
}

// couple (top, bot) with q = (c, s, t, r): top gets phase e^{i th}, then
//   top' = t*pt + i*r*bot ; bot' = i*r*pt + t*bot.   (verified R5/R6)
__device__ __forceinline__ void couple(const float4 q, float2& top, float2& bot)
{
    const float pr = q.x * top.x - q.y * top.y;
    const float pi = q.x * top.y + q.y * top.x;
    const float ntx = q.z * pr - q.w * bot.y;
    const float nty = q.z * pi + q.w * bot.x;
    const float nbx = q.z * bot.x - q.w * pi;
    const float nby = q.z * bot.y + q.w * pr;
    top = make_float2(ntx, nty);
    bot = make_float2(nbx, nby);
}

// ---------------------------------------------------------------------------
// Kernel 2: wave-per-column scan, ZERO barriers.
// Block = 1 wave (64 lanes), grid = 512 (one column each, 2 waves/CU).
// Lane l owns pairs 4l..4l+3 = rows [8l, 8l+8): T[j] = row 8l+2j,
// B[j] = row 8l+2j+1, all in registers for the whole scan.
//   Even layer: pair 4l+j = (T[j], B[j])          — lane-local.
//   Odd  layer: pair 4l+j = (B[j], T[j+1]) j<3;   — lane-local.
//               pair 4l+3 = (B[3], next lane's T[0]) — one float2
//               shfl_down + couple + shfl_up per layer. Lane 63's pair 255
//               uses the identity coef (precomputed), so its garbage recv
//               value is provably untouched/unused. Lane 0 keeps T[0]
//               (row 0 is untouched by odd layers).
// Coefs double-buffered in registers: next step's 16 float4 issued before
// current step's compute — L2 latency fully hidden. No LDS, no syncthreads.
// ---------------------------------------------------------------------------
__global__ __launch_bounds__(64) void mesh_wave_kernel(
    const float4* __restrict__ coefE,
    const float4* __restrict__ coefO,
    const float* __restrict__ pout,
    float* __restrict__ out, const int out_size)
{
    const int l   = threadIdx.x;   // lane 0..63
    const int col = blockIdx.x;    // column 0..511

    float2 T[4], B[4];
#pragma unroll
    for (int j = 0; j < 4; ++j) {
        T[j] = make_float2((8 * l + 2 * j     == col) ? 1.0f : 0.0f, 0.0f);
        B[j] = make_float2((8 * l + 2 * j + 1 == col) ? 1.0f : 0.0f, 0.0f);
    }

    const int lb = 4 * l;  // this lane's pair base
    float4 cE[8], cO[8];   // current step: [layer h][pair j] at 4h+j
#pragma unroll
    for (int j = 0; j < 4; ++j) {
        cE[j]     = coefE[lb + j];
        cE[4 + j] = coefE[256 + lb + j];
        cO[j]     = coefO[lb + j];
        cO[4 + j] = coefO[256 + lb + j];
    }

#pragma unroll 1
    for (int i = 0; i < 256; ++i) {
        // ---- prefetch next step's coefs (issued before any compute) ----
        float4 nE[8], nO[8];
        const int nk = ((i < 255) ? 2 * (i + 1) : 0) * 256 + lb;
#pragma unroll
        for (int j = 0; j < 4; ++j) {
            nE[j]     = coefE[nk + j];
            nE[4 + j] = coefE[nk + 256 + j];
            nO[j]     = coefO[nk + j];
            nO[4 + j] = coefO[nk + 256 + j];
        }

        // ---- two even layers: lane-local ----
#pragma unroll
        for (int h = 0; h < 2; ++h) {
#pragma unroll
            for (int j = 0; j < 4; ++j) couple(cE[4 * h + j], T[j], B[j]);
        }

        // ---- two odd layers: one neighbor float2 per layer via shuffles ----
#pragma unroll
        for (int h = 0; h < 2; ++h) {
            float2 recv;
            recv.x = __shfl_down(T[0].x, 1);
            recv.y = __shfl_down(T[0].y, 1);
            couple(cO[4 * h + 0], B[0], T[1]);
            couple(cO[4 * h + 1], B[1], T[2]);
            couple(cO[4 * h + 2], B[2], T[3]);
            couple(cO[4 * h + 3], B[3], recv);   // lane 63: identity coef
            float2 up;
            up.x = __shfl_up(recv.x, 1);
            up.y = __shfl_up(recv.y, 1);
            if (l > 0) T[0] = up;                // lane 0: row 0 untouched
        }

        // ---- rotate buffers ----
#pragma unroll
        for (int j = 0; j < 8; ++j) { cE[j] = nE[j]; cO[j] = nO[j]; }
    }

    // ---- output phases (per row); expected output = Re(M), row-major ----
#pragma unroll
    for (int j = 0; j < 4; ++j) {
        const int r0 = 8 * l + 2 * j;
        float s0, c0, s1, c1;
        __sincosf(clamp02pi(pout[r0]),     &s0, &c0);
        __sincosf(clamp02pi(pout[r0 + 1]), &s1, &c1);
        const int i0 = r0 * 512 + col;
        const int i1 = i0 + 512;
        if (i0 < out_size) out[i0] = c0 * T[j].x - s0 * T[j].y;
        if (i1 < out_size) out[i1] = c1 * B[j].x - s1 * B[j].y;
    }
}

// ---------------------------------------------------------------------------
// Fallback (verbatim R5 kernel, known-passing) — used only if ws too small.
// ---------------------------------------------------------------------------
__global__ __launch_bounds__(256) void mesh_kernel(
    const float* __restrict__ pe, const float* __restrict__ po,
    const float* __restrict__ pout,
    const float* __restrict__ le, const float* __restrict__ ie,
    const float* __restrict__ lo, const float* __restrict__ io,
    float* __restrict__ out, const int out_size)
{
    const int p = threadIdx.x;
    const int b = blockIdx.x;

    __shared__ float4 P[2][256];

    P[0][p] = (p == b) ? make_float4(1.0f, 0.0f, 0.0f, 0.0f)
                       : make_float4(0.0f, 0.0f, 0.0f, 0.0f);
    P[1][p] = (p == b) ? make_float4(0.0f, 0.0f, 1.0f, 0.0f)
                       : make_float4(0.0f, 0.0f, 0.0f, 0.0f);

#pragma unroll 1
    for (int i = 0; i < 256; ++i) {
        const int e0 = (2 * i) * 256 + p, e1 = e0 + 256;
        const float pe0 = pe[e0], le0 = le[e0], ie0 = ie[e0];
        const float pe1 = pe[e1], le1 = le[e1], ie1 = ie[e1];
        float po0 = 0.0f, lo0 = 0.0f, io0 = 0.0f;
        float po1 = 0.0f, lo1 = 0.0f, io1 = 0.0f;
        if (p < 255) {
            const int o0 = (2 * i) * 255 + p, o1 = o0 + 255;
            po0 = po[o0]; lo0 = lo[o0]; io0 = io[o0];
            po1 = po[o1]; lo1 = lo[o1]; io1 = io[o1];
        }

        float4 v0 = P[0][p];
        float4 v1 = P[1][p];
#pragma unroll
        for (int j = 0; j < 2; ++j) {
            float s, c;
            __sincosf(clamp02pi(j ? pe1 : pe0), &s, &c);
            const float a  = sqrtf(1.0f - (j ? le1 : le0));
            const float tt = a * sqrtf(0.5f + (j ? ie1 : ie0));
            const float rr = a * sqrtf(0.5f - (j ? ie1 : ie0));
            {
                const float ptr_ = c * v0.x - s * v0.y;
                const float pti_ = c * v0.y + s * v0.x;
                v0 = make_float4(tt * ptr_ - rr * v0.w, tt * pti_ + rr * v0.z,
                                 tt * v0.z - rr * pti_, tt * v0.w + rr * ptr_);
            }
            {
                const float ptr_ = c * v1.x - s * v1.y;
                const float pti_ = c * v1.y + s * v1.x;
                v1 = make_float4(tt * ptr_ - rr * v1.w, tt * pti_ + rr * v1.z,
                                 tt * v1.z - rr * pti_, tt * v1.w + rr * ptr_);
            }
        }
        P[0][p] = v0;
        P[1][p] = v1;
        __syncthreads();

        if (p < 255) {
            float2 top0 = make_float2(P[0][p].z, P[0][p].w);
            float2 bot0 = make_float2(P[0][p + 1].x, P[0][p + 1].y);
            float2 top1 = make_float2(P[1][p].z, P[1][p].w);
            float2 bot1 = make_float2(P[1][p + 1].x, P[1][p + 1].y);
#pragma unroll
            for (int j = 0; j < 2; ++j) {
                float s, c;
                __sincosf(clamp02pi(j ? po1 : po0), &s, &c);
                const float a  = sqrtf(1.0f - (j ? lo1 : lo0));
                const float tt = a * sqrtf(0.5f + (j ? io1 : io0));
                const float rr = a * sqrtf(0.5f - (j ? io1 : io0));
                {
                    const float ptr_ = c * top0.x - s * top0.y;
                    const float pti_ = c * top0.y + s * top0.x;
                    const float nbx = tt * bot0.x - rr * pti_;
                    const float nby = tt * bot0.y + rr * ptr_;
                    top0 = make_float2(tt * ptr_ - rr * bot0.y, tt * pti_ + rr * bot0.x);
                    bot0 = make_float2(nbx, nby);
                }
                {
                    const float ptr_ = c * top1.x - s * top1.y;
                    const float pti_ = c * top1.y + s * top1.x;
                    const float nbx = tt * bot1.x - rr * pti_;
                    const float nby = tt * bot1.y + rr * ptr_;
                    top1 = make_float2(tt * ptr_ - rr * bot1.y, tt * pti_ + rr * bot1.x);
                    bot1 = make_float2(nbx, nby);
                }
            }
            P[0][p].z = top0.x; P[0][p].w = top0.y;
            P[0][p + 1].x = bot0.x; P[0][p + 1].y = bot0.y;
            P[1][p].z = top1.x; P[1][p].w = top1.y;
            P[1][p + 1].x = bot1.x; P[1][p + 1].y = bot1.y;
        }
        __syncthreads();
    }

    const float4 v0 = P[0][p];
    const float4 v1 = P[1][p];
    float s0, c0, s1, c1;
    __sincosf(clamp02pi(pout[2 * p]),     &s0, &c0);
    __sincosf(clamp02pi(pout[2 * p + 1]), &s1, &c1);

    float4 w0, w1;
    w0.x = c0 * v0.x - s0 * v0.y;  w0.y = c0 * v0.y + s0 * v0.x;
    w0.z = c0 * v1.x - s0 * v1.y;  w0.w = c0 * v1.y + s0 * v1.x;
    w1.x = c1 * v0.z - s1 * v0.w;  w1.y = c1 * v0.w + s1 * v0.z;
    w1.z = c1 * v1.z - s1 * v1.w;  w1.w = c1 * v1.w + s1 * v1.z;

    const int i0 = (2 * p) * 512 + 2 * b;
    const int i1 = (2 * p + 1) * 512 + 2 * b;
    if (i0 + 1 < out_size) *(float2*)(out + i0) = make_float2(w0.x, w0.z);
    if (i1 + 1 < out_size) *(float2*)(out + i1) = make_float2(w1.x, w1.z);
}

extern "C" void kernel_launch(void* const* d_in, const int* in_sizes, int n_in,
                              void* d_out, int out_size, void* d_ws, size_t ws_size,
                              hipStream_t stream)
{
    const float* pe   = (const float*)d_in[0];  // pc_even_phases  [512][256]
    const float* po   = (const float*)d_in[1];  // pc_odd_phases   [512][255]
    const float* pout = (const float*)d_in[2];  // pc_out_phases   [512]
    const float* le   = (const float*)d_in[3];  // mmi_loss_even   [512][256]
    const float* ie   = (const float*)d_in[4];  // mmi_imb_even    [512][256]
    const float* lo   = (const float*)d_in[5];  // mmi_loss_odd    [512][255]
    const float* io   = (const float*)d_in[6];  // mmi_imb_odd     [512][255]

    const size_t need = (size_t)2 * 512 * 256 * sizeof(float4);  // 4 MB
    if (ws_size >= need) {
        float4* coefE = (float4*)d_ws;
        float4* coefO = coefE + 512 * 256;
        coef_kernel<<<512, 256, 0, stream>>>(pe, po, le, ie, lo, io, coefE, coefO);
        mesh_wave_kernel<<<512, 64, 0, stream>>>(coefE, coefO, pout,
                                                 (float*)d_out, out_size);
    } else {
        mesh_kernel<<<256, 256, 0, stream>>>(pe, po, pout, le, ie, lo, io,
                                             (float*)d_out, out_size);
    }
}